// Round 7
// baseline (391.300 us; speedup 1.0000x reference)
//
#include <hip/hip_runtime.h>
#include <cmath>

typedef float f4 __attribute__((ext_vector_type(4)));

#define TPB    4      // tokens per group
#define NBLK   1024   // grid
#define G      4      // groups per block (1024*4*4 = 16384 tokens)
#define SCALEF 8.0f   // alpha/rank = 32/4

__global__ __launch_bounds__(256, 2) void tmlora(
    const float* __restrict__ x,
    const float* __restrict__ A_w,
    const float* __restrict__ B_w,
    const float* __restrict__ router_w,
    const float* __restrict__ expert_vectors,
    float* __restrict__ out)
{
    const int tid  = threadIdx.x;
    const int b    = blockIdx.x;
    const int wid  = tid >> 6, lane = tid & 63;

    const f4* __restrict__ x4 = (const f4*)x;        // [ntok][1024]
    const f4* __restrict__ r4 = (const f4*)router_w; // [8][1024]
    const f4* __restrict__ a4 = (const f4*)A_w;      // [4][1024]
    const f4* __restrict__ b4 = (const f4*)B_w;      // [4096] rows (1 f4 each)

    __shared__ float red[2][4][48];   // per-wave partials, double-buffered

#define ROWPTR(W) ((W) < 8 ? (r4 + (size_t)(W) * 1024) : (a4 + (size_t)((W) - 8) * 1024))

    // ---- one-time: B_w -> 64 VGPR (thread t owns out f4-chunks {t+256j}) ----
    f4 Bc[4][4];
#pragma unroll
    for (int j = 0; j < 4; ++j)
#pragma unroll
        for (int m = 0; m < 4; ++m)
            Bc[j][m] = b4[4 * (tid + 256 * j) + m];

    // ---- prefetch x group 0 + weight row 0 ----
    f4 xv[16];
    {
        const int tok0 = b * TPB;
#pragma unroll
        for (int tk = 0; tk < 4; ++tk)
#pragma unroll
            for (int p = 0; p < 4; ++p)
                xv[tk * 4 + p] = x4[(size_t)(tok0 + tk) * 1024 + p * 256 + tid];
    }
    f4 wbuf[2][4];   // 2-slot ping-pong, 1 row lookahead
#pragma unroll
    for (int p = 0; p < 4; ++p) wbuf[0][p] = ROWPTR(0)[p * 256 + tid];

#pragma unroll 1   // keep rolled: 768 FMAs inside, 4x unroll would blow I$
    for (int q = 0; q < G; ++q) {
        const int tok0 = (q * NBLK + b) * TPB;

        // ---- FMA phase: weights from L2, 1-row lookahead ----
        float acc[4][12];
#pragma unroll
        for (int tk = 0; tk < 4; ++tk)
#pragma unroll
            for (int w = 0; w < 12; ++w) acc[tk][w] = 0.f;

#pragma unroll
        for (int w = 0; w < 12; ++w) {
            if (w + 1 < 12) {
                const f4* __restrict__ rp = ROWPTR(w + 1);
#pragma unroll
                for (int p = 0; p < 4; ++p)
                    wbuf[(w + 1) & 1][p] = rp[p * 256 + tid];
            }
#pragma unroll
            for (int p = 0; p < 4; ++p) {
                const f4 wv = wbuf[w & 1][p];
#pragma unroll
                for (int tk = 0; tk < 4; ++tk) {
                    acc[tk][w] = fmaf(xv[tk * 4 + p][0], wv[0], acc[tk][w]);
                    acc[tk][w] = fmaf(xv[tk * 4 + p][1], wv[1], acc[tk][w]);
                    acc[tk][w] = fmaf(xv[tk * 4 + p][2], wv[2], acc[tk][w]);
                    acc[tk][w] = fmaf(xv[tk * 4 + p][3], wv[3], acc[tk][w]);
                }
            }
        }

        // ---- wave butterfly: every lane gets the wave-sum ----
#pragma unroll
        for (int tk = 0; tk < 4; ++tk)
#pragma unroll
            for (int w = 0; w < 12; ++w) {
                float v = acc[tk][w];
#pragma unroll
                for (int m = 1; m < 64; m <<= 1) v += __shfl_xor(v, m, 64);
                acc[tk][w] = v;
            }
        if (lane == 0) {
#pragma unroll
            for (int tk = 0; tk < 4; ++tk)
#pragma unroll
                for (int w = 0; w < 12; ++w)
                    red[q & 1][wid][tk * 12 + w] = acc[tk][w];
        }
        __syncthreads();   // nothing in flight here -> drain is free

        // ---- NOW issue next group's prefetches (fly under epilogue+stores) ----
        if (q + 1 < G) {
            const int nt0 = ((q + 1) * NBLK + b) * TPB;
#pragma unroll
            for (int tk = 0; tk < 4; ++tk)
#pragma unroll
                for (int p = 0; p < 4; ++p)
                    xv[tk * 4 + p] = x4[(size_t)(nt0 + tk) * 1024 + p * 256 + tid];
#pragma unroll
            for (int p = 0; p < 4; ++p) wbuf[0][p] = ROWPTR(0)[p * 256 + tid];
        }

        // ---- all-lane cross-wave sum (broadcast f4 LDS reads) ----
        const f4* __restrict__ rr = (const f4*)&red[q & 1][0][0];   // [4][12] f4
#pragma unroll
        for (int tk = 0; tk < 4; ++tk)
#pragma unroll
            for (int k = 0; k < 3; ++k) {
                const f4 s = rr[0 * 12 + tk * 3 + k] + rr[1 * 12 + tk * 3 + k] +
                             rr[2 * 12 + tk * 3 + k] + rr[3 * 12 + tk * 3 + k];
                acc[tk][4 * k + 0] = s[0];
                acc[tk][4 * k + 1] = s[1];
                acc[tk][4 * k + 2] = s[2];
                acc[tk][4 * k + 3] = s[3];
            }

        // ---- all-lane epilogue: top-4 / softmax / expert mix / gelu ----
        float h[4][4];
#pragma unroll
        for (int tk = 0; tk < 4; ++tk) {
            int   idx[4];
            float val[4];
#pragma unroll
            for (int k = 0; k < 4; ++k) {
                int bi = 0; float bv = acc[tk][0];
#pragma unroll
                for (int e = 1; e < 8; ++e)
                    if (acc[tk][e] > bv) { bv = acc[tk][e]; bi = e; }
                idx[k] = bi; val[k] = bv;
#pragma unroll
                for (int e = 0; e < 8; ++e)
                    if (e == bi) acc[tk][e] = -INFINITY;   // knockout in place
            }

            float ex[4], se = 0.f;
#pragma unroll
            for (int k = 0; k < 4; ++k) { ex[k] = expf(val[k] - val[0]); se += ex[k]; }
            const float inv = 1.f / se;

            float Et[4] = {0.f, 0.f, 0.f, 0.f};
#pragma unroll
            for (int k = 0; k < 4; ++k) {
                const float wgt = ex[k] * inv;
#pragma unroll
                for (int r = 0; r < 4; ++r)
                    Et[r] = fmaf(wgt, expert_vectors[idx[k] * 4 + r], Et[r]);
            }
#pragma unroll
            for (int r = 0; r < 4; ++r) {
                const float hv = acc[tk][8 + r] + Et[r];
                h[tk][r] = SCALEF * 0.5f * hv *
                           (1.f + erff(hv * 0.70710678118654752f));
            }
        }

        // ---- store phase: nontemporal f4 stream (don't pollute L3) ----
#pragma unroll
        for (int tk = 0; tk < 4; ++tk) {
            f4* __restrict__ o4 = (f4*)out + (size_t)(tok0 + tk) * 1024;
            const float h0 = h[tk][0], h1 = h[tk][1], h2 = h[tk][2], h3 = h[tk][3];
#pragma unroll
            for (int j = 0; j < 4; ++j) {
                f4 v;
                v[0] = Bc[j][0][0] * h0 + Bc[j][0][1] * h1 + Bc[j][0][2] * h2 + Bc[j][0][3] * h3;
                v[1] = Bc[j][1][0] * h0 + Bc[j][1][1] * h1 + Bc[j][1][2] * h2 + Bc[j][1][3] * h3;
                v[2] = Bc[j][2][0] * h0 + Bc[j][2][1] * h1 + Bc[j][2][2] * h2 + Bc[j][2][3] * h3;
                v[3] = Bc[j][3][0] * h0 + Bc[j][3][1] * h1 + Bc[j][3][2] * h2 + Bc[j][3][3] * h3;
                __builtin_nontemporal_store(v, &o4[tid + 256 * j]);
            }
        }
    }
#undef ROWPTR
}

extern "C" void kernel_launch(void* const* d_in, const int* in_sizes, int n_in,
                              void* d_out, int out_size, void* d_ws, size_t ws_size,
                              hipStream_t stream) {
    const float* x        = (const float*)d_in[0];
    const float* A_w      = (const float*)d_in[1];
    const float* B_w      = (const float*)d_in[2];
    const float* router_w = (const float*)d_in[3];
    const float* ev       = (const float*)d_in[4];
    float* out            = (float*)d_out;

    tmlora<<<NBLK, 256, 0, stream>>>(x, A_w, B_w, router_w, ev, out);
}

// Round 8
// 135.039 us; speedup vs baseline: 2.8977x; 2.8977x over previous
//
#include <hip/hip_runtime.h>
#include <cmath>

typedef float f4 __attribute__((ext_vector_type(4)));

#define SCALEF 8.0f   // alpha/rank = 32/4

// One-shot: 2 tokens per 256-thread block, 8192 blocks. Small register
// footprint (~100 VGPR) so hoisted loads stay in flight; occupancy carries
// the latency hiding (16 waves/CU).
__global__ __launch_bounds__(256, 3) void tmlora(
    const float* __restrict__ x,
    const float* __restrict__ A_w,
    const float* __restrict__ B_w,
    const float* __restrict__ router_w,
    const float* __restrict__ expert_vectors,
    float* __restrict__ out)
{
    const int tid  = threadIdx.x;
    const int tok0 = blockIdx.x * 2;
    const int wid  = tid >> 6, lane = tid & 63;

    const f4* __restrict__ x4 = (const f4*)x;        // [ntok][1024]
    const f4* __restrict__ r4 = (const f4*)router_w; // [8][1024]
    const f4* __restrict__ a4 = (const f4*)A_w;      // [4][1024]
    const f4* __restrict__ b4 = (const f4*)B_w;      // [4096] rows (1 f4 each)

    __shared__ float red[4][24];   // per-wave partials (2 tok x 12)

#define ROWPTR(W) ((W) < 8 ? (r4 + (size_t)(W) * 1024) : (a4 + (size_t)((W) - 8) * 1024))

    // ---- all 8 x loads up front (stay in flight; small live set) ----
    f4 xv[8];
#pragma unroll
    for (int p = 0; p < 4; ++p)
#pragma unroll
        for (int tk = 0; tk < 2; ++tk)
            xv[tk * 4 + p] = x4[(size_t)(tok0 + tk) * 1024 + p * 256 + tid];

    // ---- weight stream: 2-slot ping-pong, 1 row lookahead ----
    f4 wbuf[2][4];
#pragma unroll
    for (int p = 0; p < 4; ++p) wbuf[0][p] = ROWPTR(0)[p * 256 + tid];

    float acc[2][12];
#pragma unroll
    for (int tk = 0; tk < 2; ++tk)
#pragma unroll
        for (int w = 0; w < 12; ++w) acc[tk][w] = 0.f;

#pragma unroll
    for (int w = 0; w < 12; ++w) {
        if (w + 1 < 12) {
            const f4* __restrict__ rp = ROWPTR(w + 1);
#pragma unroll
            for (int p = 0; p < 4; ++p)
                wbuf[(w + 1) & 1][p] = rp[p * 256 + tid];
        }
#pragma unroll
        for (int p = 0; p < 4; ++p) {
            const f4 wv = wbuf[w & 1][p];
#pragma unroll
            for (int tk = 0; tk < 2; ++tk) {
                acc[tk][w] = fmaf(xv[tk * 4 + p][0], wv[0], acc[tk][w]);
                acc[tk][w] = fmaf(xv[tk * 4 + p][1], wv[1], acc[tk][w]);
                acc[tk][w] = fmaf(xv[tk * 4 + p][2], wv[2], acc[tk][w]);
                acc[tk][w] = fmaf(xv[tk * 4 + p][3], wv[3], acc[tk][w]);
            }
        }
    }
#undef ROWPTR

    // ---- wave butterfly (24 values) ----
#pragma unroll
    for (int tk = 0; tk < 2; ++tk)
#pragma unroll
        for (int w = 0; w < 12; ++w) {
            float v = acc[tk][w];
#pragma unroll
            for (int m = 1; m < 64; m <<= 1) v += __shfl_xor(v, m, 64);
            acc[tk][w] = v;
        }
    if (lane == 0) {
#pragma unroll
        for (int tk = 0; tk < 2; ++tk)
#pragma unroll
            for (int w = 0; w < 12; ++w) red[wid][tk * 12 + w] = acc[tk][w];
    }
    __syncthreads();   // nothing in flight -> vmcnt drain is free

    // ---- all-lane cross-wave sum (broadcast f4 LDS reads) ----
    const f4* __restrict__ rr = (const f4*)&red[0][0];   // 4 waves x 6 f4
#pragma unroll
    for (int tk = 0; tk < 2; ++tk)
#pragma unroll
        for (int k = 0; k < 3; ++k) {
            const f4 s = rr[0 * 6 + tk * 3 + k] + rr[1 * 6 + tk * 3 + k] +
                         rr[2 * 6 + tk * 3 + k] + rr[3 * 6 + tk * 3 + k];
            acc[tk][4 * k + 0] = s[0];
            acc[tk][4 * k + 1] = s[1];
            acc[tk][4 * k + 2] = s[2];
            acc[tk][4 * k + 3] = s[3];
        }

    // ---- all-lane epilogue: top-4 / softmax / expert mix / exact gelu ----
    float h[2][4];
#pragma unroll
    for (int tk = 0; tk < 2; ++tk) {
        int   idx[4];
        float val[4];
#pragma unroll
        for (int k = 0; k < 4; ++k) {
            int bi = 0; float bv = acc[tk][0];
#pragma unroll
            for (int e = 1; e < 8; ++e)
                if (acc[tk][e] > bv) { bv = acc[tk][e]; bi = e; }
            idx[k] = bi; val[k] = bv;
#pragma unroll
            for (int e = 0; e < 8; ++e)
                if (e == bi) acc[tk][e] = -INFINITY;   // static-index knockout
        }

        float ex[4], se = 0.f;
#pragma unroll
        for (int k = 0; k < 4; ++k) { ex[k] = expf(val[k] - val[0]); se += ex[k]; }
        const float inv = 1.f / se;

        float Et[4] = {0.f, 0.f, 0.f, 0.f};
#pragma unroll
        for (int k = 0; k < 4; ++k) {
            const float wgt = ex[k] * inv;
#pragma unroll
            for (int r = 0; r < 4; ++r)
                Et[r] = fmaf(wgt, expert_vectors[idx[k] * 4 + r], Et[r]);
        }
#pragma unroll
        for (int r = 0; r < 4; ++r) {
            const float hv = acc[tk][8 + r] + Et[r];
            h[tk][r] = SCALEF * 0.5f * hv *
                       (1.f + erff(hv * 0.70710678118654752f));
        }
    }

    // ---- store phase: B_w from L1/L2 per-j (16 f4 loads), 8 nt stores ----
#pragma unroll
    for (int j = 0; j < 4; ++j) {
        const int c = tid + 256 * j;          // out f4-chunk within a row
        const f4 B0 = b4[4 * c + 0], B1 = b4[4 * c + 1],
                 B2 = b4[4 * c + 2], B3 = b4[4 * c + 3];
#pragma unroll
        for (int tk = 0; tk < 2; ++tk) {
            const float h0 = h[tk][0], h1 = h[tk][1],
                        h2 = h[tk][2], h3 = h[tk][3];
            f4 v;
            v[0] = B0[0] * h0 + B0[1] * h1 + B0[2] * h2 + B0[3] * h3;
            v[1] = B1[0] * h0 + B1[1] * h1 + B1[2] * h2 + B1[3] * h3;
            v[2] = B2[0] * h0 + B2[1] * h1 + B2[2] * h2 + B2[3] * h3;
            v[3] = B3[0] * h0 + B3[1] * h1 + B3[2] * h2 + B3[3] * h3;
            __builtin_nontemporal_store(
                v, (f4*)out + (size_t)(tok0 + tk) * 1024 + c);
        }
    }
}

extern "C" void kernel_launch(void* const* d_in, const int* in_sizes, int n_in,
                              void* d_out, int out_size, void* d_ws, size_t ws_size,
                              hipStream_t stream) {
    const float* x        = (const float*)d_in[0];
    const float* A_w      = (const float*)d_in[1];
    const float* B_w      = (const float*)d_in[2];
    const float* router_w = (const float*)d_in[3];
    const float* ev       = (const float*)d_in[4];
    float* out            = (float*)d_out;

    const int ntok = in_sizes[0] / 4096;     // 16384
    tmlora<<<ntok / 2, 256, 0, stream>>>(x, A_w, B_w, router_w, ev, out);
}